// Round 6
// baseline (114.223 us; speedup 1.0000x reference)
//
#include <hip/hip_runtime.h>

// PDF sampler (NeRF importance sampling) — search-free, analytic merge.
// 8 rays per wave (MLP + ILP), wave-private LDS regions (no block barrier),
// coalesced float4 output stores per wave.
//
// Identities (exact in fp32 for these inputs):
//  * ends[i] == starts[i+1]  =>  existing_bins == [starts[0..63], ends[63]]
//  * u_j = j/64 exact; t_i = ceil(64*cdf[i]) exact  =>  sample group ind=k+1
//    covers j in [t_k, t_{k+1}); within a group u in [c0, c1) so t in [0,1)
//    (no clamp, no 0/0), and denom==0 => empty group (ceil monotone).
//  * stable-merge positions (no sort): pos(eb[i]) = i + t_i,
//    pos(smp_j) = j + ind_j = j + owner + 1, sample 64 = e_last at slot 129.

#define NUM_RAYS 524288
#define NE 64
#define HIST_PAD 0.01f
#define EPS_PAD 1e-5f

constexpr int WAVES = 4;              // waves per block
constexpr int RPW   = 8;              // rays per wave
constexpr int RPB   = WAVES * RPW;    // 32 rays per block
constexpr int BLOCK = WAVES * 64;     // 256 threads
constexpr int ROW   = 130;            // output floats per ray

// DPP helper: moved value; 0-fill on invalid source lanes (bound_ctrl) and on
// row_mask-disabled rows (old = 0).
template <int CTRL, int ROW_MASK = 0xf>
__device__ __forceinline__ float dpp0f(float x) {
    return __int_as_float(
        __builtin_amdgcn_update_dpp(0, __float_as_int(x), CTRL, ROW_MASK, 0xf, true));
}

__global__ __launch_bounds__(BLOCK) void pdf_sample_kernel(
    const float* __restrict__ weights,
    const float* __restrict__ starts,
    const float* __restrict__ ends,
    float* __restrict__ out)
{
    __shared__ __align__(16) float s_o[RPB][ROW];          // 16640 B

    const int lane = threadIdx.x & 63;
    const int wvid = threadIdx.x >> 6;
    const int ray0 = blockIdx.x * RPB + wvid * RPW;        // multiple of 8

    // ---- packed broadcast loads: lane&7 -> ends[ray0+r][63] (1 VMEM instr) ----
    const float e_pack = ends[(unsigned)(ray0 + (lane & 7)) * NE + 63u];

    // ---- issue all full-width loads up front (17 loads in flight) ----
    float wl[RPW], sl[RPW];
    #pragma unroll
    for (int r = 0; r < RPW; ++r) {
        const unsigned ib = (unsigned)(ray0 + r) * NE + (unsigned)lane;
        wl[r] = weights[ib];
        sl[r] = starts [ib];
    }

    float* const srow_base = &s_o[wvid * RPW][0];          // wave-private 4160 B

    // ---- per-ray compute (8 independent chains -> ILP) ----
    #pragma unroll
    for (int r = 0; r < RPW; ++r) {
        float* const srow = srow_base + r * ROW;
        const float w      = wl[r] + HIST_PAD;
        const float s      = sl[r];                        // eb[lane]
        const float e_last = __int_as_float(
            __builtin_amdgcn_readlane(__float_as_int(e_pack), r));   // eb[64]

        // inclusive scan (pure-VALU DPP)
        float c = w;
        c += dpp0f<0x111>(c);          // row_shr:1
        c += dpp0f<0x112>(c);          // row_shr:2
        c += dpp0f<0x114>(c);          // row_shr:4
        c += dpp0f<0x118>(c);          // row_shr:8
        c += dpp0f<0x142, 0xa>(c);     // row_bcast:15 -> rows 1,3
        c += dpp0f<0x143, 0xc>(c);     // row_bcast:31 -> rows 2,3

        const float ws      = __int_as_float(__builtin_amdgcn_readlane(__float_as_int(c), 63));
        const float padding = fmaxf(EPS_PAD - ws, 0.0f);
        float rtot;
        asm("v_rcp_f32 %0, %1" : "=v"(rtot) : "v"(ws + padding));
        const float pad64 = padding * (1.0f / 64.0f);

        // cdf[lane+1] (clamped) and t_{lane+1} = ceil(64*cdf)
        const float cdfk = fminf(fmaf((float)(lane + 1), pad64, c) * rtot, 1.0f);
        const int   tcur = (int)ceilf(cdfk * 64.0f);       // in [0,64]

        const float c0p   = dpp0f<0x138>(cdfk);            // wave_shr:1 -> cdf[lane], lane0 -> 0
        const int   tprev = (int)ceilf(c0p * 64.0f);       // bitwise == lane-1's tcur
        float b1n = dpp0f<0x130>(s);                       // wave_shl:1 -> eb[lane+1]
        if (lane == 63) b1n = e_last;

        // existing bin: pos = lane + t_lane
        srow[lane + tprev] = s;

        // owned samples j in [tprev, tcur): pos = j + lane + 1
        const float denom = cdfk - c0p;                    // > 0 whenever loop runs
        float rden;
        asm("v_rcp_f32 %0, %1" : "=v"(rden) : "v"(denom));
        const float slope = (b1n - s) * rden;              // inf/nan only if loop empty
        float v = fmaf((float)tprev, 1.0f / 64.0f, -c0p);  // u_{tprev} - c0 >= 0
        for (int j = tprev; j < tcur; ++j) {
            srow[j + lane + 1] = fmaf(v, slope, s);
            v += 1.0f / 64.0f;
        }

        if (lane == 63) {
            srow[2 * NE + 1] = e_last;                     // sample 64 -> slot 129
            srow[NE + tcur]  = e_last;                     // eb[64] at 64 + t_64
            for (int j = tcur; j < NE; ++j)                // degenerate tail (never in practice)
                srow[j + NE + 1] = e_last;
        }
    }

    // wave-local: all LDS traffic above is this wave's own region
    asm volatile("s_waitcnt lgkmcnt(0)" ::: "memory");

    // ---- wave-coalesced store: 8 rows = 1040 floats = 260 float4, contiguous ----
    const float4* sf = (const float4*)srow_base;           // 16B-aligned (4160B region)
    float4* ob = (float4*)(out + (size_t)ray0 * ROW);      // ray0%8==0 -> 16B-aligned
    #pragma unroll
    for (int k = 0; k < 4; ++k)
        ob[lane + k * 64] = sf[lane + k * 64];
    if (lane < 4)
        ob[lane + 256] = sf[lane + 256];
}

extern "C" void kernel_launch(void* const* d_in, const int* in_sizes, int n_in,
                              void* d_out, int out_size, void* d_ws, size_t ws_size,
                              hipStream_t stream) {
    const float* weights = (const float*)d_in[0];
    const float* starts  = (const float*)d_in[1];
    const float* ends    = (const float*)d_in[2];
    float* out = (float*)d_out;

    const int grid = NUM_RAYS / RPB;                       // 16384 blocks
    pdf_sample_kernel<<<grid, BLOCK, 0, stream>>>(weights, starts, ends, out);
}

// Round 8
// 107.008 us; speedup vs baseline: 1.0674x; 1.0674x over previous
//
#include <hip/hip_runtime.h>

// PDF sampler (NeRF importance sampling) — search-free, analytic merge.
// 4 rays per wave, block-staged LDS output, NON-TEMPORAL final stores
// (keep the 272 MB output stream from evicting the ~300 MB input set
// out of the 256 MB Infinity Cache).
//
// Identities (exact in fp32 for these inputs):
//  * ends[i] == starts[i+1]  =>  existing_bins == [starts[0..63], ends[63]]
//  * u_j = j/64 exact; t_i = ceil(64*cdf[i]) exact  =>  sample group ind=k+1
//    covers j in [t_k, t_{k+1}); within a group u in [c0, c1) so t in [0,1)
//    (no clamp, no 0/0), and denom==0 => empty group (ceil monotone).
//  * stable-merge positions (no sort): pos(eb[i]) = i + t_i,
//    pos(smp_j) = j + ind_j = j + owner + 1, sample 64 = e_last at slot 129.

#define NUM_RAYS 524288
#define NE 64
#define HIST_PAD 0.01f
#define EPS_PAD 1e-5f

constexpr int WAVES = 4;              // waves per block
constexpr int RPW   = 4;              // rays per wave
constexpr int RPB   = WAVES * RPW;    // 16 rays per block
constexpr int BLOCK = WAVES * 64;     // 256 threads
constexpr int ROW   = 130;            // output floats per ray

typedef float f32x4 __attribute__((ext_vector_type(4)));   // nt-store-compatible

// DPP helpers: moved value; 0-fill on invalid source lanes (bound_ctrl) and on
// row_mask-disabled rows (old = 0).
template <int CTRL, int ROW_MASK = 0xf>
__device__ __forceinline__ float dpp0f(float x) {
    return __int_as_float(
        __builtin_amdgcn_update_dpp(0, __float_as_int(x), CTRL, ROW_MASK, 0xf, true));
}
template <int CTRL, int ROW_MASK = 0xf>
__device__ __forceinline__ int dpp0i(int x) {
    return __builtin_amdgcn_update_dpp(0, x, CTRL, ROW_MASK, 0xf, true);
}

__global__ __launch_bounds__(BLOCK) void pdf_sample_kernel(
    const float* __restrict__ weights,
    const float* __restrict__ starts,
    const float* __restrict__ ends,
    float* __restrict__ out)
{
    __shared__ __align__(16) float s_o[RPB][ROW];          // 8320 B = 130 lines

    const int lane = threadIdx.x & 63;
    const int wvid = threadIdx.x >> 6;
    const int ray0 = blockIdx.x * RPB + wvid * RPW;

    // packed broadcast load: lane&3 -> ends[ray0+r][63]  (1 VMEM instr / wave)
    const float e_pack = ends[(unsigned)(ray0 + (lane & 3)) * NE + 63u];

    // issue all full-width loads up front
    float wl[RPW], sl[RPW];
    #pragma unroll
    for (int r = 0; r < RPW; ++r) {
        const unsigned ib = (unsigned)(ray0 + r) * NE + (unsigned)lane;
        wl[r] = weights[ib];
        sl[r] = starts [ib];
    }

    // ---- per-ray compute (independent chains -> ILP) ----
    #pragma unroll
    for (int r = 0; r < RPW; ++r) {
        float* const srow = &s_o[wvid * RPW + r][0];
        const float w      = wl[r] + HIST_PAD;
        const float s      = sl[r];                        // eb[lane]
        const float e_last = __int_as_float(
            __builtin_amdgcn_readlane(__float_as_int(e_pack), r));   // eb[64]

        // inclusive scan (pure-VALU DPP)
        float c = w;
        c += dpp0f<0x111>(c);          // row_shr:1
        c += dpp0f<0x112>(c);          // row_shr:2
        c += dpp0f<0x114>(c);          // row_shr:4
        c += dpp0f<0x118>(c);          // row_shr:8
        c += dpp0f<0x142, 0xa>(c);     // row_bcast:15 -> rows 1,3
        c += dpp0f<0x143, 0xc>(c);     // row_bcast:31 -> rows 2,3

        const float ws      = __int_as_float(__builtin_amdgcn_readlane(__float_as_int(c), 63));
        const float padding = fmaxf(EPS_PAD - ws, 0.0f);
        float rtot;
        asm("v_rcp_f32 %0, %1" : "=v"(rtot) : "v"(ws + padding));
        const float pad64 = padding * (1.0f / 64.0f);

        // cdf[lane+1] (clamped) and t_{lane+1} = ceil(64*cdf)
        const float cdfk = fminf(fmaf((float)(lane + 1), pad64, c) * rtot, 1.0f);
        const int   tcur = (int)ceilf(cdfk * 64.0f);       // in [0,64]

        // neighbors via wave-wide DPP shifts (zero-fill edges)
        const float c0p   = dpp0f<0x138>(cdfk);            // cdf[lane], lane0 -> 0
        const int   tprev = dpp0i<0x138>(tcur);            // t_lane,   lane0 -> 0
        float b1n = dpp0f<0x130>(s);                       // eb[lane+1]
        if (lane == 63) b1n = e_last;

        // existing bin: pos = lane + t_lane
        srow[lane + tprev] = s;

        // owned samples j in [tprev, tcur): pos = j + lane + 1
        const float denom = cdfk - c0p;                    // > 0 whenever loop runs
        float rden;
        asm("v_rcp_f32 %0, %1" : "=v"(rden) : "v"(denom));
        const float slope = (b1n - s) * rden;              // inf/nan only if loop empty
        float v = fmaf((float)tprev, 1.0f / 64.0f, -c0p);  // u_{tprev} - c0 >= 0
        for (int j = tprev; j < tcur; ++j) {
            srow[j + lane + 1] = fmaf(v, slope, s);
            v += 1.0f / 64.0f;
        }

        if (lane == 63) {
            srow[2 * NE + 1] = e_last;                     // sample 64 -> slot 129
            srow[NE + tcur]  = e_last;                     // eb[64] at 64 + t_64
            for (int j = tcur; j < NE; ++j)                // degenerate tail (never in practice)
                srow[j + NE + 1] = e_last;
        }
    }

    __syncthreads();

    // ---- block-wide coalesced NON-TEMPORAL store: 2080 floats = 520 float4 ----
    const f32x4* sf = (const f32x4*)&s_o[0][0];
    f32x4* ob = (f32x4*)(out + (size_t)blockIdx.x * (RPB * ROW)); // 64B-aligned
    const int t = threadIdx.x;
    __builtin_nontemporal_store(sf[t],         &ob[t]);
    __builtin_nontemporal_store(sf[t + BLOCK], &ob[t + BLOCK]);
    if (t < RPB * ROW / 4 - 2 * BLOCK)                     // 8 tail float4s
        __builtin_nontemporal_store(sf[t + 2 * BLOCK], &ob[t + 2 * BLOCK]);
}

extern "C" void kernel_launch(void* const* d_in, const int* in_sizes, int n_in,
                              void* d_out, int out_size, void* d_ws, size_t ws_size,
                              hipStream_t stream) {
    const float* weights = (const float*)d_in[0];
    const float* starts  = (const float*)d_in[1];
    const float* ends    = (const float*)d_in[2];
    float* out = (float*)d_out;

    const int grid = NUM_RAYS / RPB;                       // 32768 blocks
    pdf_sample_kernel<<<grid, BLOCK, 0, stream>>>(weights, starts, ends, out);
}